// Round 3
// baseline (452.878 us; speedup 1.0000x reference)
//
#include <hip/hip_runtime.h>
#include <hip/hip_bf16.h>
#include <hip/hip_fp16.h>

#define B_SZ 2
#define L_SZ 4096
#define DM 768
#define DSt 16
#define E_SZ 1536
#define M_SZ (B_SZ*L_SZ)      /* 8192 rows */
#define KF 1568               /* final GEMM K: 1536 x_act + 32 us_pad */
#define LN_EPSF 1e-5f

typedef _Float16 h16;
typedef __attribute__((ext_vector_type(8))) _Float16 half8;
typedef __attribute__((ext_vector_type(4))) float f32x4;

__device__ inline void gload_lds16(const void* g, void* l) {
  __builtin_amdgcn_global_load_lds((const __attribute__((address_space(1))) unsigned int*)g,
                                   (__attribute__((address_space(3))) unsigned int*)l,
                                   16, 0, 0);
}

// ---------------- slim weight prep: W_xp->f16 (coalesced), WsmT, bsm ----------------
__global__ void wprep_kernel(const float* __restrict__ W_xp, const float* __restrict__ W_dt,
                             const float* __restrict__ b_xp, const float* __restrict__ b_dt,
                             h16* __restrict__ W_xp_h, h16* __restrict__ WsmT,
                             float* __restrict__ bsm) {
  const int S1 = E_SZ * 784;
  const int S2 = 128 * E_SZ;
  const int total = S1 + S2 + 32;
  for (int idx = blockIdx.x * 256 + threadIdx.x; idx < total; idx += gridDim.x * 256) {
    if (idx < S1) {
      W_xp_h[idx] = (h16)W_xp[idx];
    } else if (idx < S1 + S2) {
      int t = idx - S1;
      int n = t / E_SZ, k = t % E_SZ;
      float v = 0.f;
      if (n < 16)      v = W_xp[(size_t)k * 784 + 768 + n];
      else if (n < 32) v = W_dt[(size_t)k * DSt + (n - 16)];
      WsmT[t] = (h16)v;
    } else {
      int c = idx - S1 - S2;
      bsm[c] = (c < 16) ? b_xp[768 + c] : b_dt[c - 16];
    }
  }
}

// ---------------- LDS-tiled transpose f32->f16: dst[c*ldd+coff+r] (+)= src[r*C+c] ----------------
__global__ void transpose_f16_kernel(const float* __restrict__ src, int R, int C,
                                     h16* __restrict__ dst, int ldd, int coff, int add) {
  __shared__ h16 tile[64][65];
  int r0 = blockIdx.y * 64, c0 = blockIdx.x * 64;
  int lane = threadIdx.x & 63, grp = threadIdx.x >> 6;
#pragma unroll
  for (int i = 0; i < 16; ++i) {
    int r = grp + i * 4;
    tile[r][lane] = (h16)src[(size_t)(r0 + r) * C + c0 + lane];
  }
  __syncthreads();
#pragma unroll
  for (int i = 0; i < 16; ++i) {
    int c = grp + i * 4;
    size_t di = (size_t)(c0 + c) * ldd + coff + r0 + lane;
    h16 v = tile[lane][c];
    if (add) dst[di] = (h16)((float)dst[di] + (float)v);
    else dst[di] = v;
  }
}

// ---------------- W_combT (us weight) into W_bigT cols 1536.. + b_final ----------------
__global__ void wcomb_kernel(const float* __restrict__ W_us, const float* __restrict__ W_out,
                             const float* __restrict__ b_us, const float* __restrict__ b_xp,
                             const float* __restrict__ b_out,
                             h16* __restrict__ W_bigT, float* __restrict__ b_final) {
  int n = blockIdx.x * 64 + (threadIdx.x & 63);
  int sy = threadIdx.x >> 6;             // 0..3 -> s = sy*4 .. sy*4+3
  float acc[4] = {};
  float bacc = 0.f;
  for (int j = 0; j < DM; ++j) {
    float wv = W_out[(size_t)j * DM + n];
#pragma unroll
    for (int i = 0; i < 4; ++i) acc[i] += W_us[(sy * 4 + i) * DM + j] * wv;
    if (sy == 0) bacc += (b_us[j] + b_xp[j]) * wv;
  }
#pragma unroll
  for (int i = 0; i < 4; ++i) {
    int s = sy * 4 + i;
    W_bigT[(size_t)n * KF + 1536 + s] = (h16)acc[i];
    W_bigT[(size_t)n * KF + 1552 + s] = (h16)0.f;
  }
  if (sy == 0) b_final[n] = b_out[n] + bacc;
}

// ---------------- LayerNorm -> f16 ----------------
__global__ void ln_kernel(const float* __restrict__ x, const float* __restrict__ g,
                          const float* __restrict__ beta, h16* __restrict__ xn) {
  int m = blockIdx.x;
  const float* row = x + (size_t)m * DM;
  float s = 0.f, ss = 0.f;
  for (int i = threadIdx.x; i < DM; i += 256) {
    float v = row[i];
    s += v; ss += v * v;
  }
  for (int d = 32; d; d >>= 1) { s += __shfl_down(s, d); ss += __shfl_down(ss, d); }
  __shared__ float red0[4], red1[4];
  int wid = threadIdx.x >> 6;
  if ((threadIdx.x & 63) == 0) { red0[wid] = s; red1[wid] = ss; }
  __syncthreads();
  __shared__ float sh_mu, sh_inv;
  if (threadIdx.x == 0) {
    s  = red0[0] + red0[1] + red0[2] + red0[3];
    ss = red1[0] + red1[1] + red1[2] + red1[3];
    float mu = s * (1.f / DM);
    float var = ss * (1.f / DM) - mu * mu;
    sh_mu = mu;
    sh_inv = rsqrtf(var + LN_EPSF);
  }
  __syncthreads();
  float mu = sh_mu, inv = sh_inv;
  h16* orow = xn + (size_t)m * DM;
  for (int i = threadIdx.x; i < DM; i += 256) {
    orow[i] = (h16)((row[i] - mu) * inv * g[i] + beta[i]);
  }
}

// ---------------- f16 MFMA GEMM (m97 structure): C = A@Bt^T + bias ----------------
// A: [M][K] f16 (lda); for k >= ksplit read A2 with column origin k2off (lda2).
// Bt: [N][K] f16 (ldb). C: [M][ldc] OutT, cols >= Nreal masked.
template <typename OutT>
__global__ __launch_bounds__(256)
void gemm_f16(const h16* __restrict__ A, int lda,
              const h16* __restrict__ A2, int lda2, int ksplit, int k2off,
              const h16* __restrict__ Bt, int ldb,
              const float* __restrict__ bias,
              OutT* __restrict__ C, int ldc,
              int Nreal, int K) {
  __shared__ h16 Ash[128][32];
  __shared__ h16 Bsh[128][32];
  int tid = threadIdx.x;
  int w = tid >> 6, l = tid & 63;
  int m0 = blockIdx.y * 128;
  int n0 = blockIdx.x * 128;
  int wr = w >> 1, wc = w & 1;
  int lrow = l >> 2;
  int lcol = (l & 3) * 8;
  int fr = l & 15, fq = l >> 4;
  f32x4 acc[4][4] = {};

  for (int k0 = 0; k0 < K; k0 += 32) {
    const h16* Ap; int ldA; int kb;
    if (k0 >= ksplit) { Ap = A2; ldA = lda2; kb = k0 - k2off; }
    else              { Ap = A;  ldA = lda;  kb = k0; }
    gload_lds16(Ap + (size_t)(m0 + 16 * w + lrow) * ldA + kb + lcol,      &Ash[16 * w][0]);
    gload_lds16(Ap + (size_t)(m0 + 64 + 16 * w + lrow) * ldA + kb + lcol, &Ash[64 + 16 * w][0]);
    gload_lds16(Bt + (size_t)(n0 + 16 * w + lrow) * ldb + k0 + lcol,      &Bsh[16 * w][0]);
    gload_lds16(Bt + (size_t)(n0 + 64 + 16 * w + lrow) * ldb + k0 + lcol, &Bsh[64 + 16 * w][0]);
    __syncthreads();
    half8 af[4], bf[4];
#pragma unroll
    for (int i = 0; i < 4; ++i)
      af[i] = *(const half8*)&Ash[wr * 64 + i * 16 + fr][fq * 8];
#pragma unroll
    for (int j = 0; j < 4; ++j)
      bf[j] = *(const half8*)&Bsh[wc * 64 + j * 16 + fr][fq * 8];
#pragma unroll
    for (int i = 0; i < 4; ++i)
#pragma unroll
      for (int j = 0; j < 4; ++j)
        acc[i][j] = __builtin_amdgcn_mfma_f32_16x16x32_f16(af[i], bf[j], acc[i][j], 0, 0, 0);
    __syncthreads();
  }
#pragma unroll
  for (int i = 0; i < 4; ++i) {
#pragma unroll
    for (int j = 0; j < 4; ++j) {
      int n = n0 + wc * 64 + j * 16 + fr;
      if (n < Nreal) {
        float b = bias ? bias[n] : 0.f;
#pragma unroll
        for (int r = 0; r < 4; ++r) {
          int m = m0 + wr * 64 + i * 16 + fq * 4 + r;
          C[(size_t)m * ldc + n] = (OutT)(acc[i][j][r] + b);
        }
      }
    }
  }
}

// ---------------- depthwise causal conv (4 taps) + silu ----------------
__global__ void conv_silu_kernel(const h16* __restrict__ x_in, const float* __restrict__ Wc,
                                 const float* __restrict__ bc, h16* __restrict__ x_act) {
  int idx = blockIdx.x * 256 + threadIdx.x;
  const int E8 = E_SZ / 8;
  if (idx >= M_SZ * E8) return;
  int e8 = idx % E8;
  int m = idx / E8;
  int t = m % L_SZ;
  int e0 = e8 * 8;
  const h16* p0 = x_in + (size_t)m * E_SZ + e0;
  half8 r0 = *(const half8*)p0;
  half8 r1 = {}, r2 = {}, r3 = {};
  if (t >= 1) r1 = *(const half8*)(p0 - E_SZ);
  if (t >= 2) r2 = *(const half8*)(p0 - 2 * E_SZ);
  if (t >= 3) r3 = *(const half8*)(p0 - 3 * E_SZ);
  half8 out;
#pragma unroll
  for (int j = 0; j < 8; ++j) {
    int e = e0 + j;
    float4 wv = *reinterpret_cast<const float4*>(&Wc[e * 4]);
    float acc = bc[e] + (float)r0[j] * wv.w + (float)r1[j] * wv.z
              + (float)r2[j] * wv.y + (float)r3[j] * wv.x;
    float sg = 1.f / (1.f + expf(-acc));
    out[j] = (h16)(acc * sg);
  }
  *(half8*)(x_act + (size_t)m * E_SZ + e0) = out;
}

// ---------------- fused softplus/exp + 4-wave block scan + us -> us_pad f16 ----------------
__global__ void scan_fused_kernel(const float* __restrict__ sd, h16* __restrict__ us_pad) {
  int chain = blockIdx.x;            // 0..31
  int b = chain >> 4, s = chain & 15;
  int t = threadIdx.x;               // 0..255, each owns 16 timesteps
  int mloc0 = t * 16;
  size_t gbase = ((size_t)b * L_SZ + mloc0) * 32;
  float dtv[16], av[16], btv[16];
  float A = 1.f, Bc = 0.f;
#pragma unroll
  for (int i = 0; i < 16; ++i) {
    float pre = sd[gbase + (size_t)i * 32 + 16 + s];
    float dsv = sd[gbase + (size_t)i * 32 + s];
    float d = (pre > 20.f) ? pre : log1pf(expf(pre));
    dtv[i] = d;
    float a = expf(-d);
    av[i] = a;
    float bb = dsv * expf(-0.5f * d);
    btv[i] = bb;
    Bc = fmaf(a, Bc, bb);
    A *= a;
  }
  int lane = t & 63, w = t >> 6;
  for (int d = 1; d < 64; d <<= 1) {
    float Ao = __shfl_up(A, d), Bo = __shfl_up(Bc, d);
    if (lane >= d) { Bc = fmaf(A, Bo, Bc); A *= Ao; }
  }
  __shared__ float wA[4], wB[4];
  if (lane == 63) { wA[w] = A; wB[w] = Bc; }
  __syncthreads();
  float pA = 1.f, pB = 0.f;
  for (int i = 0; i < 4; ++i)
    if (i < w) { pB = fmaf(wA[i], pB, wB[i]); pA *= wA[i]; }
  float eA = __shfl_up(A, 1), eB = __shfl_up(Bc, 1);
  if (lane == 0) { eA = 1.f; eB = 0.f; }
  float v = fmaf(eA, pB, eB);        // state entering this thread's chunk
#pragma unroll
  for (int i = 0; i < 16; ++i) {
    v = fmaf(av[i], v, btv[i]);
    float d = dtv[i];
    float kk = (float)(L_SZ - 1 - (mloc0 + i));
    float e1 = expf(-kk * d);
    float em = expm1f(-kk * d);
    float den = expm1f(-d);
    if (den > -1e-30f) den = -1e-30f;
    float us = fmaf(e1, v, btv[i] * em / den);
    size_t gm = (size_t)b * L_SZ + mloc0 + i;
    us_pad[gm * 32 + s] = (h16)us;
    us_pad[gm * 32 + 16 + s] = (h16)0.f;
  }
}

// ---------------- launch ----------------
extern "C" void kernel_launch(void* const* d_in, const int* in_sizes, int n_in,
                              void* d_out, int out_size, void* d_ws, size_t ws_size,
                              hipStream_t stream) {
  const float* x      = (const float*)d_in[0];
  const float* ln_g   = (const float*)d_in[1];
  const float* ln_b   = (const float*)d_in[2];
  const float* W_in   = (const float*)d_in[3];
  const float* b_in   = (const float*)d_in[4];
  const float* W_conv = (const float*)d_in[5];
  const float* b_conv = (const float*)d_in[6];
  const float* W_xp   = (const float*)d_in[7];
  const float* b_xp   = (const float*)d_in[8];
  const float* W_dt   = (const float*)d_in[9];
  const float* b_dt   = (const float*)d_in[10];
  const float* W_us   = (const float*)d_in[11];
  const float* b_us   = (const float*)d_in[12];
  const float* W_out  = (const float*)d_in[13];
  const float* b_out  = (const float*)d_in[14];
  float* out = (float*)d_out;

  char* ws = (char*)d_ws;
  size_t off = 0;
  auto alloc = [&](size_t bytes) { void* p = ws + off; off = (off + bytes + 255) & ~(size_t)255; return p; };
  h16*   xn      = (h16*)alloc((size_t)M_SZ * DM * 2);
  h16*   x_in    = (h16*)alloc((size_t)M_SZ * E_SZ * 2);
  h16*   x_act   = (h16*)alloc((size_t)M_SZ * E_SZ * 2);
  float* sd      = (float*)alloc((size_t)M_SZ * 32 * 4);
  h16*   us_pad  = (h16*)alloc((size_t)M_SZ * 32 * 2);
  h16*   Wt_in   = (h16*)alloc((size_t)E_SZ * DM * 2);
  h16*   Wt_out  = (h16*)alloc((size_t)DM * E_SZ * 2);
  h16*   W_xp_h  = (h16*)alloc((size_t)E_SZ * 784 * 2);
  h16*   WsmT    = (h16*)alloc((size_t)128 * E_SZ * 2);
  h16*   W_bigT  = (h16*)alloc((size_t)DM * KF * 2);
  float* bsm     = (float*)alloc(32 * 4);
  float* b_final = (float*)alloc(DM * 4);

  // --- weight pipeline (per-call; weights are inputs) ---
  hipLaunchKernelGGL(wprep_kernel, dim3(4096), dim3(256), 0, stream,
                     W_xp, W_dt, b_xp, b_dt, W_xp_h, WsmT, bsm);
  hipLaunchKernelGGL(transpose_f16_kernel, dim3(E_SZ / 64, DM / 64), dim3(256), 0, stream,
                     W_in, DM, E_SZ, Wt_in, DM, 0, 0);
  hipLaunchKernelGGL(transpose_f16_kernel, dim3(DM / 64, E_SZ / 64), dim3(256), 0, stream,
                     W_out, E_SZ, DM, Wt_out, E_SZ, 0, 0);
  hipLaunchKernelGGL(wcomb_kernel, dim3(DM / 64), dim3(256), 0, stream,
                     W_us, W_out, b_us, b_xp, b_out, W_bigT, b_final);
  // W_bigT[:, :1536] = (W_xp_low @ W_out_top)^T : C[n][kk] = sum_j Wt_out[n][j] * W_xp_h[kk][j]
  hipLaunchKernelGGL((gemm_f16<h16>), dim3(E_SZ / 128, DM / 128), dim3(256), 0, stream,
                     Wt_out, E_SZ, Wt_out, E_SZ, 1 << 30, 0,
                     W_xp_h, 784, (const float*)nullptr, W_bigT, KF, E_SZ, DM);
  // W_bigT[n][768+j] += W_out[768+j][n]
  hipLaunchKernelGGL(transpose_f16_kernel, dim3(DM / 64, DM / 64), dim3(256), 0, stream,
                     W_out + (size_t)DM * DM, DM, DM, W_bigT, KF, DM, 1);

  // --- activation pipeline ---
  hipLaunchKernelGGL(ln_kernel, dim3(M_SZ), dim3(256), 0, stream, x, ln_g, ln_b, xn);
  hipLaunchKernelGGL((gemm_f16<h16>), dim3(E_SZ / 128, M_SZ / 128), dim3(256), 0, stream,
                     xn, DM, xn, DM, 1 << 30, 0,
                     Wt_in, DM, b_in, x_in, E_SZ, E_SZ, DM);
  hipLaunchKernelGGL(conv_silu_kernel, dim3((M_SZ * E_SZ / 8) / 256), dim3(256), 0, stream,
                     x_in, W_conv, b_conv, x_act);
  hipLaunchKernelGGL((gemm_f16<float>), dim3(1, M_SZ / 128), dim3(256), 0, stream,
                     x_act, E_SZ, x_act, E_SZ, 1 << 30, 0,
                     WsmT, E_SZ, bsm, sd, 32, 32, E_SZ);
  hipLaunchKernelGGL(scan_fused_kernel, dim3(B_SZ * DSt), dim3(256), 0, stream, sd, us_pad);
  hipLaunchKernelGGL((gemm_f16<float>), dim3(DM / 128, M_SZ / 128), dim3(256), 0, stream,
                     x_act, E_SZ, us_pad, 32, E_SZ, E_SZ,
                     W_bigT, KF, b_final, out, DM, DM, KF);
}

// Round 4
// 331.326 us; speedup vs baseline: 1.3669x; 1.3669x over previous
//
#include <hip/hip_runtime.h>
#include <hip/hip_bf16.h>
#include <hip/hip_fp16.h>

#define B_SZ 2
#define L_SZ 4096
#define DM 768
#define DSt 16
#define E_SZ 1536
#define M_SZ (B_SZ*L_SZ)      /* 8192 rows */
#define KF 1568               /* final GEMM K: 1536 x_act + 32 us_pad */
#define KSPLIT 6
#define LN_EPSF 1e-5f

typedef _Float16 h16;
typedef __attribute__((ext_vector_type(8))) _Float16 half8;
typedef __attribute__((ext_vector_type(4))) float f32x4;

__device__ inline void gload_lds16(const void* g, void* l) {
  __builtin_amdgcn_global_load_lds((const __attribute__((address_space(1))) unsigned int*)g,
                                   (__attribute__((address_space(3))) unsigned int*)l,
                                   16, 0, 0);
}

// ---------------- weight prep: W_xp->f16, WsmT, bsm, WusT(+bias row) ----------------
__global__ void wprep_kernel(const float* __restrict__ W_xp, const float* __restrict__ W_dt,
                             const float* __restrict__ b_xp, const float* __restrict__ b_dt,
                             const float* __restrict__ W_us, const float* __restrict__ b_us,
                             h16* __restrict__ W_xp_h, h16* __restrict__ WsmT,
                             float* __restrict__ bsm, h16* __restrict__ WusT) {
  const int S1 = E_SZ * 784;           // W_xp_h straight f16 copy
  const int S2 = 128 * E_SZ;           // WsmT [128 rows pad][1536]
  const int S3 = 32 * DM;              // WusT [32 rows][768]: 0-15 W_us, 16 bias, rest 0
  const int total = S1 + S2 + S3 + 32;
  for (int idx = blockIdx.x * 256 + threadIdx.x; idx < total; idx += gridDim.x * 256) {
    if (idx < S1) {
      W_xp_h[idx] = (h16)W_xp[idx];
    } else if (idx < S1 + S2) {
      int t = idx - S1;
      int n = t / E_SZ, k = t % E_SZ;
      float v = 0.f;
      if (n < 16)      v = W_xp[(size_t)k * 784 + 768 + n];
      else if (n < 32) v = W_dt[(size_t)k * DSt + (n - 16)];
      WsmT[t] = (h16)v;
    } else if (idx < S1 + S2 + S3) {
      int t = idx - S1 - S2;
      int s = t / DM, j = t % DM;
      float v = 0.f;
      if (s < 16)       v = W_us[(size_t)s * DM + j];
      else if (s == 16) v = b_us[j] + b_xp[j];
      WusT[t] = (h16)v;
    } else {
      int c = idx - S1 - S2 - S3;
      bsm[c] = (c < 16) ? b_xp[768 + c] : b_dt[c - 16];
    }
  }
}

// ---------------- LDS-tiled transpose f32->f16: dst[c*ldd+coff+r] (+)= src[r*C+c] ----------------
__global__ void transpose_f16_kernel(const float* __restrict__ src, int R, int C,
                                     h16* __restrict__ dst, int ldd, int coff, int add) {
  __shared__ h16 tile[64][65];
  int r0 = blockIdx.y * 64, c0 = blockIdx.x * 64;
  int lane = threadIdx.x & 63, grp = threadIdx.x >> 6;
#pragma unroll
  for (int i = 0; i < 16; ++i) {
    int r = grp + i * 4;
    tile[r][lane] = (h16)src[(size_t)(r0 + r) * C + c0 + lane];
  }
  __syncthreads();
#pragma unroll
  for (int i = 0; i < 16; ++i) {
    int c = grp + i * 4;
    size_t di = (size_t)(c0 + c) * ldd + coff + r0 + lane;
    h16 v = tile[lane][c];
    if (add) dst[di] = (h16)((float)dst[di] + (float)v);
    else dst[di] = v;
  }
}

// ---------------- assemble W_bigT cols 1536..1567 + b_final from C_comb ----------------
__global__ void wfinal_kernel(const float* __restrict__ C_comb, const float* __restrict__ b_out,
                              h16* __restrict__ W_bigT, float* __restrict__ b_final) {
  int idx = blockIdx.x * 256 + threadIdx.x;   // 768*32
  if (idx >= DM * 32) return;
  int n = idx >> 5, s = idx & 31;
  float v = (s < 16) ? C_comb[n * 32 + s] : 0.f;
  W_bigT[(size_t)n * KF + 1536 + s] = (h16)v;
  if (s == 16) b_final[n] = b_out[n] + C_comb[n * 32 + 16];
}

// ---------------- LayerNorm -> f16 ----------------
__global__ void ln_kernel(const float* __restrict__ x, const float* __restrict__ g,
                          const float* __restrict__ beta, h16* __restrict__ xn) {
  int m = blockIdx.x;
  const float* row = x + (size_t)m * DM;
  float s = 0.f, ss = 0.f;
  for (int i = threadIdx.x; i < DM; i += 256) {
    float v = row[i];
    s += v; ss += v * v;
  }
  for (int d = 32; d; d >>= 1) { s += __shfl_down(s, d); ss += __shfl_down(ss, d); }
  __shared__ float red0[4], red1[4];
  int wid = threadIdx.x >> 6;
  if ((threadIdx.x & 63) == 0) { red0[wid] = s; red1[wid] = ss; }
  __syncthreads();
  __shared__ float sh_mu, sh_inv;
  if (threadIdx.x == 0) {
    s  = red0[0] + red0[1] + red0[2] + red0[3];
    ss = red1[0] + red1[1] + red1[2] + red1[3];
    float mu = s * (1.f / DM);
    float var = ss * (1.f / DM) - mu * mu;
    sh_mu = mu;
    sh_inv = rsqrtf(var + LN_EPSF);
  }
  __syncthreads();
  float mu = sh_mu, inv = sh_inv;
  h16* orow = xn + (size_t)m * DM;
  for (int i = threadIdx.x; i < DM; i += 256) {
    orow[i] = (h16)((row[i] - mu) * inv * g[i] + beta[i]);
  }
}

// ---------------- f16 MFMA GEMM: C = A@Bt^T + bias, optional split-K over blockIdx.z --------
// A: [M][K] f16 (lda); for k >= ksplit read A2 with column origin k2off (lda2).
// Bt: [N][K] f16 (ldb). C: [M][ldc] OutT (+ blockIdx.z * csplit), cols >= Nreal masked.
template <typename OutT>
__global__ __launch_bounds__(256)
void gemm_f16(const h16* __restrict__ A, int lda,
              const h16* __restrict__ A2, int lda2, int ksplit, int k2off,
              const h16* __restrict__ Bt, int ldb,
              const float* __restrict__ bias,
              OutT* __restrict__ C, int ldc, size_t csplit,
              int Nreal, int K) {
  __shared__ h16 Ash[128][32];
  __shared__ h16 Bsh[128][32];
  int tid = threadIdx.x;
  int w = tid >> 6, l = tid & 63;
  int m0 = blockIdx.y * 128;
  int n0 = blockIdx.x * 128;
  int wr = w >> 1, wc = w & 1;
  int lrow = l >> 2;
  int lcol = (l & 3) * 8;
  int fr = l & 15, fq = l >> 4;
  int Kz = K / gridDim.z;
  int kbeg = blockIdx.z * Kz;
  C += (size_t)blockIdx.z * csplit;
  f32x4 acc[4][4] = {};

  for (int k0 = kbeg; k0 < kbeg + Kz; k0 += 32) {
    const h16* Ap; int ldA; int kb;
    if (k0 >= ksplit) { Ap = A2; ldA = lda2; kb = k0 - k2off; }
    else              { Ap = A;  ldA = lda;  kb = k0; }
    gload_lds16(Ap + (size_t)(m0 + 16 * w + lrow) * ldA + kb + lcol,      &Ash[16 * w][0]);
    gload_lds16(Ap + (size_t)(m0 + 64 + 16 * w + lrow) * ldA + kb + lcol, &Ash[64 + 16 * w][0]);
    gload_lds16(Bt + (size_t)(n0 + 16 * w + lrow) * ldb + k0 + lcol,      &Bsh[16 * w][0]);
    gload_lds16(Bt + (size_t)(n0 + 64 + 16 * w + lrow) * ldb + k0 + lcol, &Bsh[64 + 16 * w][0]);
    __syncthreads();
    half8 af[4], bf[4];
#pragma unroll
    for (int i = 0; i < 4; ++i)
      af[i] = *(const half8*)&Ash[wr * 64 + i * 16 + fr][fq * 8];
#pragma unroll
    for (int j = 0; j < 4; ++j)
      bf[j] = *(const half8*)&Bsh[wc * 64 + j * 16 + fr][fq * 8];
#pragma unroll
    for (int i = 0; i < 4; ++i)
#pragma unroll
      for (int j = 0; j < 4; ++j)
        acc[i][j] = __builtin_amdgcn_mfma_f32_16x16x32_f16(af[i], bf[j], acc[i][j], 0, 0, 0);
    __syncthreads();
  }
#pragma unroll
  for (int i = 0; i < 4; ++i) {
#pragma unroll
    for (int j = 0; j < 4; ++j) {
      int n = n0 + wc * 64 + j * 16 + fr;
      if (n < Nreal) {
        float b = bias ? bias[n] : 0.f;
#pragma unroll
        for (int r = 0; r < 4; ++r) {
          int m = m0 + wr * 64 + i * 16 + fq * 4 + r;
          C[(size_t)m * ldc + n] = (OutT)(acc[i][j][r] + b);
        }
      }
    }
  }
}

// ---------------- reduce split-K partials + bias -> sd f32 ----------------
__global__ void reduce_sd_kernel(const float* __restrict__ sd_part, const float* __restrict__ bsm,
                                 float* __restrict__ sd) {
  int idx = blockIdx.x * 256 + threadIdx.x;
  const int total = M_SZ * 32;
  if (idx >= total) return;
  float acc = bsm[idx & 31];
#pragma unroll
  for (int z = 0; z < KSPLIT; ++z) acc += sd_part[(size_t)z * total + idx];
  sd[idx] = acc;
}

// ---------------- depthwise causal conv (4 taps) + silu ----------------
__global__ void conv_silu_kernel(const h16* __restrict__ x_in, const float* __restrict__ Wc,
                                 const float* __restrict__ bc, h16* __restrict__ x_act) {
  int idx = blockIdx.x * 256 + threadIdx.x;
  const int E8 = E_SZ / 8;
  if (idx >= M_SZ * E8) return;
  int e8 = idx % E8;
  int m = idx / E8;
  int t = m % L_SZ;
  int e0 = e8 * 8;
  const h16* p0 = x_in + (size_t)m * E_SZ + e0;
  half8 r0 = *(const half8*)p0;
  half8 r1 = {}, r2 = {}, r3 = {};
  if (t >= 1) r1 = *(const half8*)(p0 - E_SZ);
  if (t >= 2) r2 = *(const half8*)(p0 - 2 * E_SZ);
  if (t >= 3) r3 = *(const half8*)(p0 - 3 * E_SZ);
  half8 out;
#pragma unroll
  for (int j = 0; j < 8; ++j) {
    int e = e0 + j;
    float4 wv = *reinterpret_cast<const float4*>(&Wc[e * 4]);
    float acc = bc[e] + (float)r0[j] * wv.w + (float)r1[j] * wv.z
              + (float)r2[j] * wv.y + (float)r3[j] * wv.x;
    float sg = 1.f / (1.f + expf(-acc));
    out[j] = (h16)(acc * sg);
  }
  *(half8*)(x_act + (size_t)m * E_SZ + e0) = out;
}

// ---------------- fused softplus/exp + 4-wave block scan + us -> us_pad f16 ----------------
__global__ void scan_fused_kernel(const float* __restrict__ sd, h16* __restrict__ us_pad) {
  int chain = blockIdx.x;            // 0..31
  int b = chain >> 4, s = chain & 15;
  int t = threadIdx.x;               // 0..255, each owns 16 timesteps
  int mloc0 = t * 16;
  size_t gbase = ((size_t)b * L_SZ + mloc0) * 32;
  float dtv[16], av[16], btv[16];
  float A = 1.f, Bc = 0.f;
#pragma unroll
  for (int i = 0; i < 16; ++i) {
    float pre = sd[gbase + (size_t)i * 32 + 16 + s];
    float dsv = sd[gbase + (size_t)i * 32 + s];
    float d = (pre > 20.f) ? pre : log1pf(expf(pre));
    dtv[i] = d;
    float a = expf(-d);
    av[i] = a;
    float bb = dsv * expf(-0.5f * d);
    btv[i] = bb;
    Bc = fmaf(a, Bc, bb);
    A *= a;
  }
  int lane = t & 63, w = t >> 6;
  for (int d = 1; d < 64; d <<= 1) {
    float Ao = __shfl_up(A, d), Bo = __shfl_up(Bc, d);
    if (lane >= d) { Bc = fmaf(A, Bo, Bc); A *= Ao; }
  }
  __shared__ float wA[4], wB[4];
  if (lane == 63) { wA[w] = A; wB[w] = Bc; }
  __syncthreads();
  float pA = 1.f, pB = 0.f;
  for (int i = 0; i < 4; ++i)
    if (i < w) { pB = fmaf(wA[i], pB, wB[i]); pA *= wA[i]; }
  float eA = __shfl_up(A, 1), eB = __shfl_up(Bc, 1);
  if (lane == 0) { eA = 1.f; eB = 0.f; }
  float v = fmaf(eA, pB, eB);        // state entering this thread's chunk
#pragma unroll
  for (int i = 0; i < 16; ++i) {
    v = fmaf(av[i], v, btv[i]);
    float d = dtv[i];
    float kk = (float)(L_SZ - 1 - (mloc0 + i));
    float e1 = expf(-kk * d);
    float em = expm1f(-kk * d);
    float den = expm1f(-d);
    if (den > -1e-30f) den = -1e-30f;
    float us = fmaf(e1, v, btv[i] * em / den);
    size_t gm = (size_t)b * L_SZ + mloc0 + i;
    us_pad[gm * 32 + s] = (h16)us;
    us_pad[gm * 32 + 16 + s] = (h16)0.f;
  }
}

// ---------------- launch ----------------
extern "C" void kernel_launch(void* const* d_in, const int* in_sizes, int n_in,
                              void* d_out, int out_size, void* d_ws, size_t ws_size,
                              hipStream_t stream) {
  const float* x      = (const float*)d_in[0];
  const float* ln_g   = (const float*)d_in[1];
  const float* ln_b   = (const float*)d_in[2];
  const float* W_in   = (const float*)d_in[3];
  const float* b_in   = (const float*)d_in[4];
  const float* W_conv = (const float*)d_in[5];
  const float* b_conv = (const float*)d_in[6];
  const float* W_xp   = (const float*)d_in[7];
  const float* b_xp   = (const float*)d_in[8];
  const float* W_dt   = (const float*)d_in[9];
  const float* b_dt   = (const float*)d_in[10];
  const float* W_us   = (const float*)d_in[11];
  const float* b_us   = (const float*)d_in[12];
  const float* W_out  = (const float*)d_in[13];
  const float* b_out  = (const float*)d_in[14];
  float* out = (float*)d_out;

  char* ws = (char*)d_ws;
  size_t off = 0;
  auto alloc = [&](size_t bytes) { void* p = ws + off; off = (off + bytes + 255) & ~(size_t)255; return p; };
  h16*   xn      = (h16*)alloc((size_t)M_SZ * DM * 2);
  h16*   x_in    = (h16*)alloc((size_t)M_SZ * E_SZ * 2);
  h16*   x_act   = (h16*)alloc((size_t)M_SZ * E_SZ * 2);
  float* sd      = (float*)alloc((size_t)M_SZ * 32 * 4);
  float* sd_part = (float*)alloc((size_t)KSPLIT * M_SZ * 32 * 4);
  h16*   us_pad  = (h16*)alloc((size_t)M_SZ * 32 * 2);
  h16*   Wt_in   = (h16*)alloc((size_t)E_SZ * DM * 2);
  h16*   Wt_out  = (h16*)alloc((size_t)DM * E_SZ * 2);
  h16*   W_xp_h  = (h16*)alloc((size_t)E_SZ * 784 * 2);
  h16*   WsmT    = (h16*)alloc((size_t)128 * E_SZ * 2);
  h16*   WusT    = (h16*)alloc((size_t)128 * DM * 2);   // 32 init + 96 pad rows
  h16*   W_bigT  = (h16*)alloc((size_t)DM * KF * 2);
  float* C_comb  = (float*)alloc((size_t)DM * 32 * 4);
  float* bsm     = (float*)alloc(32 * 4);
  float* b_final = (float*)alloc(DM * 4);

  // --- weight pipeline ---
  hipLaunchKernelGGL(wprep_kernel, dim3(2048), dim3(256), 0, stream,
                     W_xp, W_dt, b_xp, b_dt, W_us, b_us, W_xp_h, WsmT, bsm, WusT);
  hipLaunchKernelGGL(transpose_f16_kernel, dim3(E_SZ / 64, DM / 64), dim3(256), 0, stream,
                     W_in, DM, E_SZ, Wt_in, DM, 0, 0);
  hipLaunchKernelGGL(transpose_f16_kernel, dim3(DM / 64, E_SZ / 64), dim3(256), 0, stream,
                     W_out, E_SZ, DM, Wt_out, E_SZ, 0, 0);
  // W_bigT[:, :1536] = (W_xp_low @ W_out_top)^T
  hipLaunchKernelGGL((gemm_f16<h16>), dim3(E_SZ / 128, DM / 128, 1), dim3(256), 0, stream,
                     Wt_out, E_SZ, Wt_out, E_SZ, 1 << 30, 0,
                     W_xp_h, 784, (const float*)nullptr, W_bigT, KF, 0, E_SZ, DM);
  // C_comb[n][s] = sum_j Wt_out[n][j] * WusT[s][j]  (s=16 row carries bias dot)
  hipLaunchKernelGGL((gemm_f16<float>), dim3(1, DM / 128, 1), dim3(256), 0, stream,
                     Wt_out, E_SZ, Wt_out, E_SZ, 1 << 30, 0,
                     WusT, DM, (const float*)nullptr, C_comb, 32, 0, 17, DM);
  // W_bigT[n][768+j] += W_out[768+j][n]
  hipLaunchKernelGGL(transpose_f16_kernel, dim3(DM / 64, DM / 64), dim3(256), 0, stream,
                     W_out + (size_t)DM * DM, DM, DM, W_bigT, KF, DM, 1);
  hipLaunchKernelGGL(wfinal_kernel, dim3((DM * 32) / 256), dim3(256), 0, stream,
                     C_comb, b_out, W_bigT, b_final);

  // --- activation pipeline ---
  hipLaunchKernelGGL(ln_kernel, dim3(M_SZ), dim3(256), 0, stream, x, ln_g, ln_b, xn);
  hipLaunchKernelGGL((gemm_f16<h16>), dim3(E_SZ / 128, M_SZ / 128, 1), dim3(256), 0, stream,
                     xn, DM, xn, DM, 1 << 30, 0,
                     Wt_in, DM, b_in, x_in, E_SZ, 0, E_SZ, DM);
  hipLaunchKernelGGL(conv_silu_kernel, dim3((M_SZ * E_SZ / 8) / 256), dim3(256), 0, stream,
                     x_in, W_conv, b_conv, x_act);
  // sd_part[z] = x_act @ WsmT^T (K chunk z)
  hipLaunchKernelGGL((gemm_f16<float>), dim3(1, M_SZ / 128, KSPLIT), dim3(256), 0, stream,
                     x_act, E_SZ, x_act, E_SZ, 1 << 30, 0,
                     WsmT, E_SZ, (const float*)nullptr, sd_part, 32, (size_t)M_SZ * 32, 32, E_SZ);
  hipLaunchKernelGGL(reduce_sd_kernel, dim3((M_SZ * 32) / 256), dim3(256), 0, stream,
                     sd_part, bsm, sd);
  hipLaunchKernelGGL(scan_fused_kernel, dim3(B_SZ * DSt), dim3(256), 0, stream, sd, us_pad);
  hipLaunchKernelGGL((gemm_f16<float>), dim3(DM / 128, M_SZ / 128, 1), dim3(256), 0, stream,
                     x_act, E_SZ, us_pad, 32, E_SZ, E_SZ,
                     W_bigT, KF, b_final, out, DM, 0, DM, KF);
}